// Round 4
// baseline (3243.962 us; speedup 1.0000x reference)
//
#include <hip/hip_runtime.h>
#include <hip/hip_bf16.h>
#include <math.h>

#define N_NODES 50000
#define EDGES   800000
#define META    4
#define IN_DIM  512
#define NHID    128
#define NCLS    2
#define TOT_EDGES (META * EDGES)     // 3200000
#define RPB    128                   // rows per bucket
#define NBKT   391                   // ceil(50000/128) buckets per meta
#define NSUB   8                     // sub-buckets (≈ per-XCD frontiers)
#define SUBCAP 448                   // capacity per sub-bucket (mean 256, ~13 sigma)

typedef __bf16 bf16x8 __attribute__((ext_vector_type(8)));
typedef float  f32x4  __attribute__((ext_vector_type(4)));

__device__ __forceinline__ float bfbits_lo(unsigned int p) {
  return __uint_as_float((p & 0xFFFFu) << 16);
}
__device__ __forceinline__ float bfbits_hi(unsigned int p) {
  return __uint_as_float(p & 0xFFFF0000u);
}

// ---------------- pack W1 into MFMA-fragment-ready bf16 hi/lo ----------------
// frag idx = (s*8 + t)*64 + l ; element i holds W1[s*32 + (l>>4)*8 + i][t*16 + (l&15)]
__global__ __launch_bounds__(256) void pack_w1(const float* __restrict__ W1,
                                               __bf16* __restrict__ Wh,
                                               __bf16* __restrict__ Wl) {
  int idx = blockIdx.x * 256 + threadIdx.x;
  if (idx >= 16 * 8 * 64) return;
  int l = idx & 63, st = idx >> 6, t = st & 7, s = st >> 3;
  int col = t * 16 + (l & 15);
  int k0 = s * 32 + (l >> 4) * 8;
#pragma unroll
  for (int i = 0; i < 8; ++i) {
    float w = W1[(size_t)(k0 + i) * NHID + col];
    __bf16 h = (__bf16)w;
    Wh[(size_t)idx * 8 + i] = h;
    Wl[(size_t)idx * 8 + i] = (__bf16)(w - (float)h);
  }
}

// ---------------- GEMM: pre1 = x @ W1 via bf16x3 MFMA, bf16 output ----------------
__global__ __launch_bounds__(256) void gemm_mfma(const float* __restrict__ X,
                                                 const __bf16* __restrict__ Wh,
                                                 const __bf16* __restrict__ Wl,
                                                 __bf16* __restrict__ C) {
  int w = threadIdx.x >> 6, l = threadIdx.x & 63;
  int lrow = l & 15, lk = l >> 4;
  int row = blockIdx.x * 64 + w * 16 + lrow;
  int rowc = row < N_NODES ? row : N_NODES - 1;
  f32x4 acc[8] = {};
  const bf16x8* whv = (const bf16x8*)Wh;
  const bf16x8* wlv = (const bf16x8*)Wl;

  for (int s = 0; s < 16; ++s) {
    const float* ap = &X[(size_t)rowc * IN_DIM + s * 32 + lk * 8];
    float4 a0 = *reinterpret_cast<const float4*>(ap);
    float4 a1 = *reinterpret_cast<const float4*>(ap + 4);
    float av[8] = {a0.x, a0.y, a0.z, a0.w, a1.x, a1.y, a1.z, a1.w};
    bf16x8 ah, al;
#pragma unroll
    for (int i = 0; i < 8; ++i) {
      float v = av[i];
      __bf16 h = (__bf16)v;
      ah[i] = h;
      al[i] = (__bf16)(v - (float)h);
    }
    int fbase = (s * 8) * 64 + l;
#pragma unroll
    for (int t = 0; t < 8; ++t) {
      bf16x8 bh = whv[fbase + t * 64];
      bf16x8 bl = wlv[fbase + t * 64];
      acc[t] = __builtin_amdgcn_mfma_f32_16x16x32_bf16(ah, bh, acc[t], 0, 0, 0);
      acc[t] = __builtin_amdgcn_mfma_f32_16x16x32_bf16(ah, bl, acc[t], 0, 0, 0);
      acc[t] = __builtin_amdgcn_mfma_f32_16x16x32_bf16(al, bh, acc[t], 0, 0, 0);
    }
  }
  int crow0 = blockIdx.x * 64 + w * 16 + lk * 4;
#pragma unroll
  for (int t = 0; t < 8; ++t) {
    int col = t * 16 + lrow;
#pragma unroll
    for (int r = 0; r < 4; ++r) {
      int crow = crow0 + r;
      if (crow < N_NODES) C[(size_t)crow * NHID + col] = (__bf16)acc[t][r];
    }
  }
}

// ---------------- binning: edges -> [meta][bucket][sub] append lists ----------------
__global__ __launch_bounds__(256) void bin_all(const int* __restrict__ rows,
                                               const int* __restrict__ cols,
                                               const float* __restrict__ vals,
                                               int2* __restrict__ buckets,
                                               int* __restrict__ bcnt) {
  int e = blockIdx.x * 256 + threadIdx.x;
  if (e >= TOT_EDGES) return;
  int m = e / EDGES;
  int r = rows[e];
  int bslot = (m * NBKT + (r >> 7)) * NSUB + (blockIdx.x & (NSUB - 1));
  int pos = atomicAdd(&bcnt[bslot], 1);
  if (pos < SUBCAP) {
    int2 ed;
    ed.x = ((r & (RPB - 1)) << 16) | cols[e];
    ed.y = __float_as_int(vals[e]);
    buckets[(size_t)bslot * SUBCAP + pos] = ed;
  }
}

// ------- layer-1 SpMM: per-bucket LDS tile accumulate + fused BN partial stats -------
__global__ __launch_bounds__(512) void tile1(const int2* __restrict__ buckets,
                                             const int* __restrict__ bcnt,
                                             const unsigned short* __restrict__ pre1b,
                                             float* __restrict__ h1,
                                             float* __restrict__ stats, int m) {
  __shared__ float tile[RPB * NHID];   // 64 KB
  int tid = threadIdx.x;
  for (int i = tid; i < RPB * NHID / 4; i += 512)
    ((float4*)tile)[i] = make_float4(0.f, 0.f, 0.f, 0.f);
  __syncthreads();

  int bkt = blockIdx.x;
  int lane = tid & 63, wv = tid >> 6;   // 8 waves
  for (int sb = 0; sb < NSUB; ++sb) {
    int slot = (m * NBKT + bkt) * NSUB + sb;
    int n = bcnt[slot];
    n = n < SUBCAP ? n : SUBCAP;
    const int2* seg = &buckets[(size_t)slot * SUBCAP];
    for (int j = wv; j < n; j += 8) {
      int2 ed = seg[j];
      int rowrel = ed.x >> 16;
      int c = ed.x & 0xFFFF;
      float v = __int_as_float(ed.y);
      unsigned int p = ((const unsigned int*)pre1b)[(size_t)c * 64 + lane];
      float* trow = &tile[(rowrel << 7) + (lane << 1)];
      unsafeAtomicAdd(trow,     v * bfbits_lo(p));
      unsafeAtomicAdd(trow + 1, v * bfbits_hi(p));
    }
  }
  __syncthreads();

  // fused BN partial stats: 4 quarter-partials per channel
  int col = tid & 127, q4 = tid >> 7;
  float s = 0.f, q = 0.f;
  const float* tc = &tile[q4 * 32 * NHID + col];
#pragma unroll 8
  for (int rr = 0; rr < 32; ++rr) {
    float xv = tc[rr * NHID];
    s += xv;
    q = fmaf(xv, xv, q);
  }
  unsafeAtomicAdd(&stats[col], s);
  unsafeAtomicAdd(&stats[128 + col], q);

  // coalesced writeout
  int r0 = bkt << 7;
  for (int i = tid; i < RPB * NHID / 4; i += 512) {
    int r = r0 + (i >> 5);
    if (r < N_NODES)
      ((float4*)&h1[(size_t)r * NHID])[i & 31] = ((float4*)tile)[i];
  }
}

// ------- BN apply + relu + @W2 -------
__global__ __launch_bounds__(256) void bn_apply_kernel(const float* __restrict__ h1,
                                                       const float* __restrict__ stats,
                                                       const float* __restrict__ W2,
                                                       float* __restrict__ pre2) {
  int lane = threadIdx.x & 63;
  int wv = threadIdx.x >> 6;
  int n = blockIdx.x * 4 + wv;
  if (n >= N_NODES) return;
  const float inv_n = 1.0f / (float)N_NODES;
  float c0 = 0.f, c1 = 0.f;
#pragma unroll
  for (int t = 0; t < 2; ++t) {
    int h = lane + t * 64;
    float mean = stats[h] * inv_n;
    float var = stats[128 + h] * inv_n - mean * mean;
    float rs = rsqrtf(var + 1e-3f);
    float x = h1[(size_t)n * NHID + h];
    float y = (x - mean) * rs;
    y = y > 0.f ? y : 0.f;
    c0 = fmaf(y, W2[h * 2 + 0], c0);
    c1 = fmaf(y, W2[h * 2 + 1], c1);
  }
  for (int off = 32; off; off >>= 1) {
    c0 += __shfl_down(c0, off);
    c1 += __shfl_down(c1, off);
  }
  if (lane == 0) {
    pre2[(size_t)n * 2 + 0] = c0;
    pre2[(size_t)n * 2 + 1] = c1;
  }
}

// ------- layer-2 SpMM: per-bucket tiny LDS tile, all metas -------
__global__ __launch_bounds__(256) void tile2(const int2* __restrict__ buckets,
                                             const int* __restrict__ bcnt,
                                             const float* __restrict__ pre2,
                                             float* __restrict__ h2) {
  __shared__ float t2[RPB * 2];
  int tid = threadIdx.x;
  t2[tid] = 0.f;
  __syncthreads();
  int m = blockIdx.y, bkt = blockIdx.x;
  const float2* p2 = (const float2*)(pre2 + (size_t)m * N_NODES * 2);
  for (int sb = 0; sb < NSUB; ++sb) {
    int slot = (m * NBKT + bkt) * NSUB + sb;
    int n = bcnt[slot];
    n = n < SUBCAP ? n : SUBCAP;
    const int2* seg = &buckets[(size_t)slot * SUBCAP];
    for (int j = tid; j < n; j += 256) {
      int2 ed = seg[j];
      int rowrel = ed.x >> 16;
      int c = ed.x & 0xFFFF;
      float v = __int_as_float(ed.y);
      float2 p = p2[c];
      unsafeAtomicAdd(&t2[rowrel * 2 + 0], v * p.x);
      unsafeAtomicAdd(&t2[rowrel * 2 + 1], v * p.y);
    }
  }
  __syncthreads();
  int r = bkt * RPB + (tid >> 1);
  if (r < N_NODES)
    h2[((size_t)m * N_NODES + r) * 2 + (tid & 1)] = t2[tid];
}

// ---------------- attention dot ----------------
__global__ __launch_bounds__(256) void att_dot_kernel(const float* __restrict__ h2,
                                                      const float* __restrict__ w_omega,
                                                      float* __restrict__ vacc) {
  float acc[16] = {};
  int stride = gridDim.x * blockDim.x;
  for (int i = blockIdx.x * blockDim.x + threadIdx.x; i < N_NODES * NCLS; i += stride) {
    float4 w = *reinterpret_cast<const float4*>(&w_omega[(size_t)i * 4]);
#pragma unroll
    for (int m = 0; m < 4; ++m) {
      float f = h2[(size_t)m * (N_NODES * NCLS) + i];
      acc[m * 4 + 0] = fmaf(f, w.x, acc[m * 4 + 0]);
      acc[m * 4 + 1] = fmaf(f, w.y, acc[m * 4 + 1]);
      acc[m * 4 + 2] = fmaf(f, w.z, acc[m * 4 + 2]);
      acc[m * 4 + 3] = fmaf(f, w.w, acc[m * 4 + 3]);
    }
  }
#pragma unroll
  for (int q = 0; q < 16; ++q) {
    float v = acc[q];
    for (int off = 32; off; off >>= 1) v += __shfl_down(v, off);
    if ((threadIdx.x & 63) == 0) atomicAdd(&vacc[q], v);
  }
}

// ---------------- attention finalize ----------------
__global__ void att_final_kernel(const float* __restrict__ vacc,
                                 const float* __restrict__ b_omega,
                                 const float* __restrict__ u_omega,
                                 float* __restrict__ alphas) {
  if (threadIdx.x == 0 && blockIdx.x == 0) {
    float s[4];
    for (int m = 0; m < 4; ++m) {
      float sm = 0.f;
      for (int j = 0; j < 4; ++j)
        sm += tanhf(vacc[m * 4 + j] + b_omega[j]) * u_omega[j];
      s[m] = sm;
    }
    float mx = fmaxf(fmaxf(s[0], s[1]), fmaxf(s[2], s[3]));
    float ex[4], den = 0.f;
    for (int m = 0; m < 4; ++m) { ex[m] = expf(s[m] - mx); den += ex[m]; }
    for (int m = 0; m < 4; ++m) alphas[m] = ex[m] / den;
  }
}

// ---------------- fused sum of squares over all 5 params ----------------
#define SQ0 400000            // w_omega
#define SQ1 (SQ0 + 65536)     // + W1
#define SQ2 (SQ1 + 256)       // + W2
#define SQ3 (SQ2 + 4)         // + b_omega
#define SQ4 (SQ3 + 4)         // + u_omega
__global__ __launch_bounds__(256) void sumsq_all(const float* __restrict__ w_omega,
                                                 const float* __restrict__ W1,
                                                 const float* __restrict__ W2,
                                                 const float* __restrict__ b_omega,
                                                 const float* __restrict__ u_omega,
                                                 float* __restrict__ out) {
  float s = 0.f;
  int stride = gridDim.x * blockDim.x;
  for (int i = blockIdx.x * blockDim.x + threadIdx.x; i < SQ4; i += stride) {
    float v;
    if (i < SQ0) v = w_omega[i];
    else if (i < SQ1) v = W1[i - SQ0];
    else if (i < SQ2) v = W2[i - SQ1];
    else if (i < SQ3) v = b_omega[i - SQ2];
    else v = u_omega[i - SQ3];
    s = fmaf(v, v, s);
  }
  for (int off = 32; off; off >>= 1) s += __shfl_down(s, off);
  if ((threadIdx.x & 63) == 0) atomicAdd(out, s);
}

// ---------------- per-node CE / acc / mask sums ----------------
__global__ __launch_bounds__(256) void loss_kernel(const float* __restrict__ h2,
                                                   const float* __restrict__ alphas,
                                                   const float* __restrict__ label,
                                                   const float* __restrict__ mask,
                                                   float* __restrict__ scal) {
  int n = blockIdx.x * blockDim.x + threadIdx.x;
  float msum = 0.f, cesum = 0.f, accsum = 0.f;
  if (n < N_NODES) {
    float a0 = alphas[0], a1 = alphas[1], a2 = alphas[2], a3 = alphas[3];
    const int S = N_NODES * NCLS;
    float l0 = a0 * h2[n * 2] + a1 * h2[S + n * 2] + a2 * h2[2 * S + n * 2] + a3 * h2[3 * S + n * 2];
    float l1 = a0 * h2[n * 2 + 1] + a1 * h2[S + n * 2 + 1] + a2 * h2[2 * S + n * 2 + 1] + a3 * h2[3 * S + n * 2 + 1];
    float mx = fmaxf(l0, l1);
    float lse = mx + logf(expf(l0 - mx) + expf(l1 - mx));
    float lb0 = label[n * 2], lb1 = label[n * 2 + 1];
    float ce = -(lb0 * (l0 - lse) + lb1 * (l1 - lse));
    int pred = (l1 > l0) ? 1 : 0;
    int larg = (lb1 > lb0) ? 1 : 0;
    float corr = (pred == larg) ? 1.f : 0.f;
    float mk = mask[n];
    msum = mk;
    cesum = ce * mk;
    accsum = corr * mk;
  }
  for (int off = 32; off; off >>= 1) {
    msum += __shfl_down(msum, off);
    cesum += __shfl_down(cesum, off);
    accsum += __shfl_down(accsum, off);
  }
  if ((threadIdx.x & 63) == 0) {
    atomicAdd(&scal[0], msum);
    atomicAdd(&scal[1], cesum);
    atomicAdd(&scal[2], accsum);
  }
}

__global__ void final_kernel(const float* __restrict__ scal, float* __restrict__ out) {
  if (threadIdx.x == 0 && blockIdx.x == 0) {
    out[0] = 5e-4f * 0.5f * scal[3] + scal[1] / scal[0];
    out[1] = scal[2] / scal[0];
  }
}

extern "C" void kernel_launch(void* const* d_in, const int* in_sizes, int n_in,
                              void* d_out, int out_size, void* d_ws, size_t ws_size,
                              hipStream_t stream) {
  const float* x       = (const float*)d_in[0];
  const float* W1      = (const float*)d_in[1];
  const float* W2      = (const float*)d_in[2];
  const float* w_omega = (const float*)d_in[3];
  const float* b_omega = (const float*)d_in[4];
  const float* u_omega = (const float*)d_in[5];
  const int*   sup_rows = (const int*)d_in[6];
  const int*   sup_cols = (const int*)d_in[7];
  const float* sup_vals = (const float*)d_in[8];
  const float* label   = (const float*)d_in[9];
  const float* mask    = (const float*)d_in[10];
  float* out = (float*)d_out;

  float* ws = (float*)d_ws;
  // offsets in floats
  __bf16* pre1b   = (__bf16*)ws;                 // 6.4M bf16 = 3.2M floats
  float*  h1m     = ws + 3200000;                // 6.4M f32
  float*  pre2    = ws + 9600000;                // 400k f32 [META][N][2]
  float*  h2      = ws + 10000000;               // 400k f32 [META][N][2]
  int2*   buckets = (int2*)(ws + 10400000);      // 12512*448 int2 = 11,210,752 ints
  int*    bcnt    = (int*)(ws + 21610752);       // 12,512 ints
  float*  stats   = ws + 21623264;               // 1024 f [META][256]
  float*  scal    = ws + 21624288;               // 8 f
  float*  vacc    = ws + 21624296;               // 16 f
  float*  alphas  = ws + 21624312;               // 4 f
  __bf16* Wh      = (__bf16*)(ws + 21624316);    // 65536 bf16
  __bf16* Wl      = (__bf16*)(ws + 21657084);    // 65536 bf16

  // ---- GEMM path: pack W1 then bf16x3 MFMA, bf16 pre1 out ----
  pack_w1<<<dim3(32), dim3(256), 0, stream>>>(W1, Wh, Wl);
  gemm_mfma<<<dim3(782), dim3(256), 0, stream>>>(x, Wh, Wl, pre1b);

  // ---- zero bucket counters + stats/scal/vacc ----
  hipMemsetAsync(bcnt, 0, META * NBKT * NSUB * sizeof(int), stream);
  hipMemsetAsync(stats, 0, (1024 + 8 + 16) * sizeof(float), stream);

  // ---- bin all edges once ----
  bin_all<<<dim3((TOT_EDGES + 255) / 256), dim3(256), 0, stream>>>(
      sup_rows, sup_cols, sup_vals, buckets, bcnt);

  // ---- per meta: layer-1 tile accumulate (+fused BN stats) -> bn_apply ----
  for (int m = 0; m < META; ++m) {
    tile1<<<dim3(NBKT), dim3(512), 0, stream>>>(buckets, bcnt, (const unsigned short*)pre1b,
                                                h1m, stats + m * 256, m);
    bn_apply_kernel<<<dim3(12500), dim3(256), 0, stream>>>(
        h1m, stats + m * 256, W2, pre2 + (size_t)m * N_NODES * NCLS);
  }

  // ---- layer-2 SpMM, all metas ----
  tile2<<<dim3(NBKT, META), dim3(256), 0, stream>>>(buckets, bcnt, pre2, h2);

  att_dot_kernel<<<dim3(64), dim3(256), 0, stream>>>(h2, w_omega, vacc);
  att_final_kernel<<<dim3(1), dim3(64), 0, stream>>>(vacc, b_omega, u_omega, alphas);

  sumsq_all<<<dim3(128), dim3(256), 0, stream>>>(w_omega, W1, W2, b_omega, u_omega, scal + 3);

  loss_kernel<<<dim3(196), dim3(256), 0, stream>>>(h2, alphas, label, mask, scal);
  final_kernel<<<dim3(1), dim3(64), 0, stream>>>(scal, out);
}

// Round 5
// 1305.092 us; speedup vs baseline: 2.4856x; 2.4856x over previous
//
#include <hip/hip_runtime.h>
#include <hip/hip_bf16.h>
#include <math.h>

#define N_NODES 50000
#define EDGES   800000
#define META    4
#define IN_DIM  512
#define NHID    128
#define NCLS    2
#define TOT_ROWS  (META * N_NODES)   // 200000
#define TOT_EDGES (META * EDGES)     // 3200000
#define SCAN_NB 196                  // ceil(200000/1024)

typedef __bf16 bf16x8 __attribute__((ext_vector_type(8)));
typedef float  f32x4  __attribute__((ext_vector_type(4)));

__device__ __forceinline__ float bfbits_lo(unsigned int p) {
  return __uint_as_float((p & 0xFFFFu) << 16);
}
__device__ __forceinline__ float bfbits_hi(unsigned int p) {
  return __uint_as_float(p & 0xFFFF0000u);
}

// ---------------- pack W1 into MFMA-fragment-ready bf16 hi/lo ----------------
// frag idx = (s*8 + t)*64 + l ; element i holds W1[s*32 + (l>>4)*8 + i][t*16 + (l&15)]
__global__ __launch_bounds__(256) void pack_w1(const float* __restrict__ W1,
                                               __bf16* __restrict__ Wh,
                                               __bf16* __restrict__ Wl) {
  int idx = blockIdx.x * 256 + threadIdx.x;
  if (idx >= 16 * 8 * 64) return;
  int l = idx & 63, st = idx >> 6, t = st & 7, s = st >> 3;
  int col = t * 16 + (l & 15);
  int k0 = s * 32 + (l >> 4) * 8;
#pragma unroll
  for (int i = 0; i < 8; ++i) {
    float w = W1[(size_t)(k0 + i) * NHID + col];
    __bf16 h = (__bf16)w;
    Wh[(size_t)idx * 8 + i] = h;
    Wl[(size_t)idx * 8 + i] = (__bf16)(w - (float)h);
  }
}

// ---------------- GEMM: pre1 = x @ W1 via bf16x3 MFMA, bf16 output ----------------
__global__ __launch_bounds__(256) void gemm_mfma(const float* __restrict__ X,
                                                 const __bf16* __restrict__ Wh,
                                                 const __bf16* __restrict__ Wl,
                                                 __bf16* __restrict__ C) {
  int w = threadIdx.x >> 6, l = threadIdx.x & 63;
  int lrow = l & 15, lk = l >> 4;
  int row = blockIdx.x * 64 + w * 16 + lrow;
  int rowc = row < N_NODES ? row : N_NODES - 1;
  f32x4 acc[8] = {};
  const bf16x8* whv = (const bf16x8*)Wh;
  const bf16x8* wlv = (const bf16x8*)Wl;

  for (int s = 0; s < 16; ++s) {
    const float* ap = &X[(size_t)rowc * IN_DIM + s * 32 + lk * 8];
    float4 a0 = *reinterpret_cast<const float4*>(ap);
    float4 a1 = *reinterpret_cast<const float4*>(ap + 4);
    float av[8] = {a0.x, a0.y, a0.z, a0.w, a1.x, a1.y, a1.z, a1.w};
    bf16x8 ah, al;
#pragma unroll
    for (int i = 0; i < 8; ++i) {
      float v = av[i];
      __bf16 h = (__bf16)v;
      ah[i] = h;
      al[i] = (__bf16)(v - (float)h);
    }
    int fbase = (s * 8) * 64 + l;
#pragma unroll
    for (int t = 0; t < 8; ++t) {
      bf16x8 bh = whv[fbase + t * 64];
      bf16x8 bl = wlv[fbase + t * 64];
      acc[t] = __builtin_amdgcn_mfma_f32_16x16x32_bf16(ah, bh, acc[t], 0, 0, 0);
      acc[t] = __builtin_amdgcn_mfma_f32_16x16x32_bf16(ah, bl, acc[t], 0, 0, 0);
      acc[t] = __builtin_amdgcn_mfma_f32_16x16x32_bf16(al, bh, acc[t], 0, 0, 0);
    }
  }
  int crow0 = blockIdx.x * 64 + w * 16 + lk * 4;
#pragma unroll
  for (int t = 0; t < 8; ++t) {
    int col = t * 16 + lrow;
#pragma unroll
    for (int r = 0; r < 4; ++r) {
      int crow = crow0 + r;
      if (crow < N_NODES) C[(size_t)crow * NHID + col] = (__bf16)acc[t][r];
    }
  }
}

// ---------------- CSR build (all 4 metas, concatenated row space) ----------------
__global__ __launch_bounds__(256) void hist_all(const int* __restrict__ rows,
                                                int* __restrict__ counts) {
  int e = blockIdx.x * 256 + threadIdx.x;
  if (e < TOT_EDGES) {
    int m = e / EDGES;
    atomicAdd(&counts[m * N_NODES + rows[e]], 1);
  }
}

__global__ __launch_bounds__(256) void scan1_kernel(const int* __restrict__ counts,
                                                    int* __restrict__ row_ptr,
                                                    int* __restrict__ blk) {
  __shared__ int lds[256];
  int b = blockIdx.x, t = threadIdx.x;
  int base = b * 1024 + t * 4;
  int v[4];
  int s = 0;
#pragma unroll
  for (int k = 0; k < 4; ++k) {
    int i = base + k;
    v[k] = (i < TOT_ROWS) ? counts[i] : 0;
    s += v[k];
  }
  lds[t] = s;
  __syncthreads();
  for (int off = 1; off < 256; off <<= 1) {
    int add = (t >= off) ? lds[t - off] : 0;
    __syncthreads();
    lds[t] += add;
    __syncthreads();
  }
  int run = (t > 0) ? lds[t - 1] : 0;
  if (t == 255) blk[b] = lds[255];
#pragma unroll
  for (int k = 0; k < 4; ++k) {
    int i = base + k;
    if (i < TOT_ROWS) row_ptr[i] = run;
    run += v[k];
  }
}

__global__ void scan2_kernel(int* __restrict__ blk) {
  if (threadIdx.x == 0 && blockIdx.x == 0) {
    int run = 0;
    for (int i = 0; i < SCAN_NB; ++i) { int t = blk[i]; blk[i] = run; run += t; }
  }
}

__global__ __launch_bounds__(256) void scan3_kernel(int* __restrict__ row_ptr,
                                                    int* __restrict__ cursor,
                                                    const int* __restrict__ blk) {
  int i = blockIdx.x * 256 + threadIdx.x;
  if (i < TOT_ROWS) {
    int v = row_ptr[i] + blk[i >> 10];
    row_ptr[i] = v;
    cursor[i] = v;
  }
  if (i == 0) row_ptr[TOT_ROWS] = TOT_EDGES;
}

// single 8B store per edge (col, val) -> one partial line instead of two
__global__ __launch_bounds__(256) void scatter_all(const int* __restrict__ rows,
                                                   const int* __restrict__ colsin,
                                                   const float* __restrict__ valsin,
                                                   int* __restrict__ cursor,
                                                   int2* __restrict__ csr_ed) {
  int e = blockIdx.x * 256 + threadIdx.x;
  if (e >= TOT_EDGES) return;
  int m = e / EDGES;
  int pos = atomicAdd(&cursor[m * N_NODES + rows[e]], 1);
  int2 ed;
  ed.x = colsin[e];
  ed.y = __float_as_int(valsin[e]);
  csr_ed[pos] = ed;
}

// ------- layer-1 SpMM gather (all metas) + fused BN partial stats, bf16 in/out -------
__global__ __launch_bounds__(256) void gather1_all(const int* __restrict__ row_ptr,
                                                   const int2* __restrict__ csr_ed,
                                                   const unsigned int* __restrict__ pre1u,
                                                   unsigned int* __restrict__ h1u,
                                                   float* __restrict__ stats) {
  __shared__ float reds[4 * 128];
  __shared__ float redq[4 * 128];
  int tid = threadIdx.x;
  int wv = tid >> 6, lane = tid & 63;
  int m = blockIdx.y;
  int r = blockIdx.x * 4 + wv;
  int gr = m * N_NODES + r;
  int start = row_ptr[gr], end = row_ptr[gr + 1];
  float a0 = 0.f, a1 = 0.f;   // channels 2*lane, 2*lane+1

  int j = start;
  if (j < end && (j & 1)) {
    int2 ed = csr_ed[j];
    float v = __int_as_float(ed.y);
    unsigned int p = pre1u[(size_t)ed.x * 64 + lane];
    a0 = fmaf(v, bfbits_lo(p), a0);
    a1 = fmaf(v, bfbits_hi(p), a1);
    ++j;
  }
  for (; j + 1 < end; j += 2) {
    int4 e2 = *reinterpret_cast<const int4*>(&csr_ed[j]);
    float v0 = __int_as_float(e2.y);
    float v1 = __int_as_float(e2.w);
    unsigned int p0 = pre1u[(size_t)e2.x * 64 + lane];
    unsigned int p1 = pre1u[(size_t)e2.z * 64 + lane];
    a0 = fmaf(v0, bfbits_lo(p0), a0);
    a1 = fmaf(v0, bfbits_hi(p0), a1);
    a0 = fmaf(v1, bfbits_lo(p1), a0);
    a1 = fmaf(v1, bfbits_hi(p1), a1);
  }
  if (j < end) {
    int2 ed = csr_ed[j];
    float v = __int_as_float(ed.y);
    unsigned int p = pre1u[(size_t)ed.x * 64 + lane];
    a0 = fmaf(v, bfbits_lo(p), a0);
    a1 = fmaf(v, bfbits_hi(p), a1);
  }

  // store h1 row as bf16 pair
  unsigned int lo = (__builtin_bit_cast(unsigned int, a0) >> 16);
  // round-to-nearest-even via cast for accuracy:
  __bf16 b0 = (__bf16)a0, b1 = (__bf16)a1;
  unsigned short u0 = __builtin_bit_cast(unsigned short, b0);
  unsigned short u1 = __builtin_bit_cast(unsigned short, b1);
  h1u[(size_t)gr * 64 + lane] = ((unsigned int)u1 << 16) | u0;
  (void)lo;

  // fused BN partial stats (f32 pre-rounding values)
  reds[wv * 128 + 2 * lane]     = a0;
  reds[wv * 128 + 2 * lane + 1] = a1;
  redq[wv * 128 + 2 * lane]     = a0 * a0;
  redq[wv * 128 + 2 * lane + 1] = a1 * a1;
  __syncthreads();
  if (tid < 128) {
    float s = reds[tid] + reds[128 + tid] + reds[256 + tid] + reds[384 + tid];
    float q = redq[tid] + redq[128 + tid] + redq[256 + tid] + redq[384 + tid];
    atomicAdd(&stats[m * 256 + tid], s);
    atomicAdd(&stats[m * 256 + 128 + tid], q);
  }
}

// ------- BN apply + relu + @W2 (all metas), bf16 h1 in -------
__global__ __launch_bounds__(256) void bn_apply_all(const unsigned int* __restrict__ h1u,
                                                    const float* __restrict__ stats,
                                                    const float* __restrict__ W2,
                                                    float* __restrict__ pre2) {
  int lane = threadIdx.x & 63;
  int wv = threadIdx.x >> 6;
  int m = blockIdx.y;
  int n = blockIdx.x * 4 + wv;
  const float inv_n = 1.0f / (float)N_NODES;
  const float* st = stats + m * 256;
  unsigned int p = h1u[((size_t)m * N_NODES + n) * 64 + lane];
  float c0 = 0.f, c1 = 0.f;
#pragma unroll
  for (int t = 0; t < 2; ++t) {
    int h = 2 * lane + t;
    float mean = st[h] * inv_n;
    float var = st[128 + h] * inv_n - mean * mean;
    float rs = rsqrtf(var + 1e-3f);
    float x = t == 0 ? bfbits_lo(p) : bfbits_hi(p);
    float y = (x - mean) * rs;
    y = y > 0.f ? y : 0.f;
    c0 = fmaf(y, W2[h * 2 + 0], c0);
    c1 = fmaf(y, W2[h * 2 + 1], c1);
  }
  for (int off = 32; off; off >>= 1) {
    c0 += __shfl_down(c0, off);
    c1 += __shfl_down(c1, off);
  }
  if (lane == 0) {
    pre2[((size_t)m * N_NODES + n) * 2 + 0] = c0;
    pre2[((size_t)m * N_NODES + n) * 2 + 1] = c1;
  }
}

// ---------------- layer-2 SpMM gather (all metas) ----------------
__global__ __launch_bounds__(256) void gather2_all(const int* __restrict__ row_ptr,
                                                   const int2* __restrict__ csr_ed,
                                                   const float* __restrict__ pre2,
                                                   float* __restrict__ h2) {
  int r = blockIdx.x * 256 + threadIdx.x;
  int m = blockIdx.y;
  if (r >= N_NODES) return;
  int start = row_ptr[m * N_NODES + r], end = row_ptr[m * N_NODES + r + 1];
  const float2* p2 = (const float2*)(pre2 + (size_t)m * N_NODES * 2);
  float a0 = 0.f, a1 = 0.f;
  for (int j = start; j < end; ++j) {
    int2 ed = csr_ed[j];
    float v = __int_as_float(ed.y);
    float2 p = p2[ed.x];
    a0 = fmaf(v, p.x, a0);
    a1 = fmaf(v, p.y, a1);
  }
  h2[((size_t)m * N_NODES + r) * 2 + 0] = a0;
  h2[((size_t)m * N_NODES + r) * 2 + 1] = a1;
}

// ---------------- attention dot ----------------
__global__ __launch_bounds__(256) void att_dot_kernel(const float* __restrict__ h2,
                                                      const float* __restrict__ w_omega,
                                                      float* __restrict__ vacc) {
  float acc[16] = {};
  int stride = gridDim.x * blockDim.x;
  for (int i = blockIdx.x * blockDim.x + threadIdx.x; i < N_NODES * NCLS; i += stride) {
    float4 w = *reinterpret_cast<const float4*>(&w_omega[(size_t)i * 4]);
#pragma unroll
    for (int m = 0; m < 4; ++m) {
      float f = h2[(size_t)m * (N_NODES * NCLS) + i];
      acc[m * 4 + 0] = fmaf(f, w.x, acc[m * 4 + 0]);
      acc[m * 4 + 1] = fmaf(f, w.y, acc[m * 4 + 1]);
      acc[m * 4 + 2] = fmaf(f, w.z, acc[m * 4 + 2]);
      acc[m * 4 + 3] = fmaf(f, w.w, acc[m * 4 + 3]);
    }
  }
#pragma unroll
  for (int q = 0; q < 16; ++q) {
    float v = acc[q];
    for (int off = 32; off; off >>= 1) v += __shfl_down(v, off);
    if ((threadIdx.x & 63) == 0) atomicAdd(&vacc[q], v);
  }
}

// ---------------- attention finalize ----------------
__global__ void att_final_kernel(const float* __restrict__ vacc,
                                 const float* __restrict__ b_omega,
                                 const float* __restrict__ u_omega,
                                 float* __restrict__ alphas) {
  if (threadIdx.x == 0 && blockIdx.x == 0) {
    float s[4];
    for (int m = 0; m < 4; ++m) {
      float sm = 0.f;
      for (int j = 0; j < 4; ++j)
        sm += tanhf(vacc[m * 4 + j] + b_omega[j]) * u_omega[j];
      s[m] = sm;
    }
    float mx = fmaxf(fmaxf(s[0], s[1]), fmaxf(s[2], s[3]));
    float ex[4], den = 0.f;
    for (int m = 0; m < 4; ++m) { ex[m] = expf(s[m] - mx); den += ex[m]; }
    for (int m = 0; m < 4; ++m) alphas[m] = ex[m] / den;
  }
}

// ---------------- fused sum of squares over all 5 params ----------------
#define SQ0 400000            // w_omega
#define SQ1 (SQ0 + 65536)     // + W1
#define SQ2 (SQ1 + 256)       // + W2
#define SQ3 (SQ2 + 4)         // + b_omega
#define SQ4 (SQ3 + 4)         // + u_omega
__global__ __launch_bounds__(256) void sumsq_all(const float* __restrict__ w_omega,
                                                 const float* __restrict__ W1,
                                                 const float* __restrict__ W2,
                                                 const float* __restrict__ b_omega,
                                                 const float* __restrict__ u_omega,
                                                 float* __restrict__ out) {
  float s = 0.f;
  int stride = gridDim.x * blockDim.x;
  for (int i = blockIdx.x * blockDim.x + threadIdx.x; i < SQ4; i += stride) {
    float v;
    if (i < SQ0) v = w_omega[i];
    else if (i < SQ1) v = W1[i - SQ0];
    else if (i < SQ2) v = W2[i - SQ1];
    else if (i < SQ3) v = b_omega[i - SQ2];
    else v = u_omega[i - SQ3];
    s = fmaf(v, v, s);
  }
  for (int off = 32; off; off >>= 1) s += __shfl_down(s, off);
  if ((threadIdx.x & 63) == 0) atomicAdd(out, s);
}

// ---------------- per-node CE / acc / mask sums ----------------
__global__ __launch_bounds__(256) void loss_kernel(const float* __restrict__ h2,
                                                   const float* __restrict__ alphas,
                                                   const float* __restrict__ label,
                                                   const float* __restrict__ mask,
                                                   float* __restrict__ scal) {
  int n = blockIdx.x * blockDim.x + threadIdx.x;
  float msum = 0.f, cesum = 0.f, accsum = 0.f;
  if (n < N_NODES) {
    float a0 = alphas[0], a1 = alphas[1], a2 = alphas[2], a3 = alphas[3];
    const int S = N_NODES * NCLS;
    float l0 = a0 * h2[n * 2] + a1 * h2[S + n * 2] + a2 * h2[2 * S + n * 2] + a3 * h2[3 * S + n * 2];
    float l1 = a0 * h2[n * 2 + 1] + a1 * h2[S + n * 2 + 1] + a2 * h2[2 * S + n * 2 + 1] + a3 * h2[3 * S + n * 2 + 1];
    float mx = fmaxf(l0, l1);
    float lse = mx + logf(expf(l0 - mx) + expf(l1 - mx));
    float lb0 = label[n * 2], lb1 = label[n * 2 + 1];
    float ce = -(lb0 * (l0 - lse) + lb1 * (l1 - lse));
    int pred = (l1 > l0) ? 1 : 0;
    int larg = (lb1 > lb0) ? 1 : 0;
    float corr = (pred == larg) ? 1.f : 0.f;
    float mk = mask[n];
    msum = mk;
    cesum = ce * mk;
    accsum = corr * mk;
  }
  for (int off = 32; off; off >>= 1) {
    msum += __shfl_down(msum, off);
    cesum += __shfl_down(cesum, off);
    accsum += __shfl_down(accsum, off);
  }
  if ((threadIdx.x & 63) == 0) {
    atomicAdd(&scal[0], msum);
    atomicAdd(&scal[1], cesum);
    atomicAdd(&scal[2], accsum);
  }
}

__global__ void final_kernel(const float* __restrict__ scal, float* __restrict__ out) {
  if (threadIdx.x == 0 && blockIdx.x == 0) {
    out[0] = 5e-4f * 0.5f * scal[3] + scal[1] / scal[0];
    out[1] = scal[2] / scal[0];
  }
}

extern "C" void kernel_launch(void* const* d_in, const int* in_sizes, int n_in,
                              void* d_out, int out_size, void* d_ws, size_t ws_size,
                              hipStream_t stream) {
  const float* x       = (const float*)d_in[0];
  const float* W1      = (const float*)d_in[1];
  const float* W2      = (const float*)d_in[2];
  const float* w_omega = (const float*)d_in[3];
  const float* b_omega = (const float*)d_in[4];
  const float* u_omega = (const float*)d_in[5];
  const int*   sup_rows = (const int*)d_in[6];
  const int*   sup_cols = (const int*)d_in[7];
  const float* sup_vals = (const float*)d_in[8];
  const float* label   = (const float*)d_in[9];
  const float* mask    = (const float*)d_in[10];
  float* out = (float*)d_out;

  float* ws = (float*)d_ws;
  // offsets in floats
  __bf16* pre1b   = (__bf16*)ws;                 // [N][128] bf16 = 3.2M f
  unsigned int* h1u = (unsigned int*)(ws + 3200000);   // [META][N][64] u32 (bf16x2) = 12.8M f
  float*  pre2    = ws + 16000000;               // 400k f [META][N][2]
  float*  h2      = ws + 16400000;               // 400k f [META][N][2]
  int2*   csr_ed  = (int2*)(ws + 16800000);      // 3.2M int2 = 6.4M f
  int*    row_ptr = (int*)(ws + 23200000);       // 200,001
  int*    cursor  = (int*)(ws + 23400064);       // 200,000
  int*    counts  = (int*)(ws + 23600064);       // 200,000
  int*    blk     = (int*)(ws + 23800064);       // 256
  float*  stats   = ws + 23800320;               // 1024 [META][256]
  float*  scal    = ws + 23801344;               // 8
  float*  vacc    = ws + 23801352;               // 16
  float*  alphas  = ws + 23801368;               // 4
  __bf16* Wh      = (__bf16*)(ws + 23801372);    // 65536 bf16
  __bf16* Wl      = (__bf16*)(ws + 23834140);    // 65536 bf16

  // ---- GEMM path ----
  pack_w1<<<dim3(32), dim3(256), 0, stream>>>(W1, Wh, Wl);
  gemm_mfma<<<dim3(782), dim3(256), 0, stream>>>(x, Wh, Wl, pre1b);

  // ---- zero counters + stats/scal/vacc ----
  hipMemsetAsync(counts, 0, TOT_ROWS * sizeof(int), stream);
  hipMemsetAsync(stats, 0, (1024 + 8 + 16) * sizeof(float), stream);

  // ---- CSR build, all 4 metas ----
  hist_all<<<dim3(12500), dim3(256), 0, stream>>>(sup_rows, counts);
  scan1_kernel<<<dim3(SCAN_NB), dim3(256), 0, stream>>>(counts, row_ptr, blk);
  scan2_kernel<<<dim3(1), dim3(64), 0, stream>>>(blk);
  scan3_kernel<<<dim3(782), dim3(256), 0, stream>>>(row_ptr, cursor, blk);
  scatter_all<<<dim3(12500), dim3(256), 0, stream>>>(sup_rows, sup_cols, sup_vals,
                                                     cursor, csr_ed);

  // ---- layer-1 gather (+fused BN stats), all metas ----
  gather1_all<<<dim3(12500, META), dim3(256), 0, stream>>>(
      row_ptr, csr_ed, (const unsigned int*)pre1b, h1u, stats);

  // ---- BN apply + W2, all metas ----
  bn_apply_all<<<dim3(12500, META), dim3(256), 0, stream>>>(h1u, stats, W2, pre2);

  // ---- layer-2 gather, all metas ----
  gather2_all<<<dim3(196, META), dim3(256), 0, stream>>>(row_ptr, csr_ed, pre2, h2);

  att_dot_kernel<<<dim3(64), dim3(256), 0, stream>>>(h2, w_omega, vacc);
  att_final_kernel<<<dim3(1), dim3(64), 0, stream>>>(vacc, b_omega, u_omega, alphas);

  sumsq_all<<<dim3(128), dim3(256), 0, stream>>>(w_omega, W1, W2, b_omega, u_omega, scal + 3);

  loss_kernel<<<dim3(196), dim3(256), 0, stream>>>(h2, alphas, label, mask, scal);
  final_kernel<<<dim3(1), dim3(64), 0, stream>>>(scal, out);
}

// Round 6
// 823.651 us; speedup vs baseline: 3.9385x; 1.5845x over previous
//
#include <hip/hip_runtime.h>
#include <hip/hip_bf16.h>
#include <math.h>

#define N_NODES 50000
#define EDGES   800000
#define META    4
#define IN_DIM  512
#define NHID    128
#define NCLS    2
#define TOT_ROWS  (META * N_NODES)   // 200000
#define TOT_EDGES (META * EDGES)     // 3200000
#define SCAN_NB 196                  // ceil(200000/1024)

typedef __bf16 bf16x8 __attribute__((ext_vector_type(8)));
typedef float  f32x4  __attribute__((ext_vector_type(4)));

__device__ __forceinline__ float bfbits_lo(unsigned int p) {
  return __uint_as_float((p & 0xFFFFu) << 16);
}
__device__ __forceinline__ float bfbits_hi(unsigned int p) {
  return __uint_as_float(p & 0xFFFF0000u);
}
__device__ __forceinline__ unsigned int pack_bf16x2(float a, float b) {
  __bf16 ba = (__bf16)a, bb = (__bf16)b;
  return ((unsigned int)__builtin_bit_cast(unsigned short, bb) << 16) |
         (unsigned int)__builtin_bit_cast(unsigned short, ba);
}

// ---------------- pack W1 into MFMA-fragment-ready bf16 hi/lo ----------------
// frag idx = (s*8 + t)*64 + l ; element i holds W1[s*32 + (l>>4)*8 + i][t*16 + (l&15)]
__global__ __launch_bounds__(256) void pack_w1(const float* __restrict__ W1,
                                               __bf16* __restrict__ Wh,
                                               __bf16* __restrict__ Wl) {
  int idx = blockIdx.x * 256 + threadIdx.x;
  if (idx >= 16 * 8 * 64) return;
  int l = idx & 63, st = idx >> 6, t = st & 7, s = st >> 3;
  int col = t * 16 + (l & 15);
  int k0 = s * 32 + (l >> 4) * 8;
#pragma unroll
  for (int i = 0; i < 8; ++i) {
    float w = W1[(size_t)(k0 + i) * NHID + col];
    __bf16 h = (__bf16)w;
    Wh[(size_t)idx * 8 + i] = h;
    Wl[(size_t)idx * 8 + i] = (__bf16)(w - (float)h);
  }
}

// ---------------- GEMM: pre1 = x @ W1 via bf16x3 MFMA, bf16 output ----------------
__global__ __launch_bounds__(256) void gemm_mfma(const float* __restrict__ X,
                                                 const __bf16* __restrict__ Wh,
                                                 const __bf16* __restrict__ Wl,
                                                 __bf16* __restrict__ C) {
  int w = threadIdx.x >> 6, l = threadIdx.x & 63;
  int lrow = l & 15, lk = l >> 4;
  int row = blockIdx.x * 64 + w * 16 + lrow;
  int rowc = row < N_NODES ? row : N_NODES - 1;
  f32x4 acc[8] = {};
  const bf16x8* whv = (const bf16x8*)Wh;
  const bf16x8* wlv = (const bf16x8*)Wl;

  for (int s = 0; s < 16; ++s) {
    const float* ap = &X[(size_t)rowc * IN_DIM + s * 32 + lk * 8];
    float4 a0 = *reinterpret_cast<const float4*>(ap);
    float4 a1 = *reinterpret_cast<const float4*>(ap + 4);
    float av[8] = {a0.x, a0.y, a0.z, a0.w, a1.x, a1.y, a1.z, a1.w};
    bf16x8 ah, al;
#pragma unroll
    for (int i = 0; i < 8; ++i) {
      float v = av[i];
      __bf16 h = (__bf16)v;
      ah[i] = h;
      al[i] = (__bf16)(v - (float)h);
    }
    int fbase = (s * 8) * 64 + l;
#pragma unroll
    for (int t = 0; t < 8; ++t) {
      bf16x8 bh = whv[fbase + t * 64];
      bf16x8 bl = wlv[fbase + t * 64];
      acc[t] = __builtin_amdgcn_mfma_f32_16x16x32_bf16(ah, bh, acc[t], 0, 0, 0);
      acc[t] = __builtin_amdgcn_mfma_f32_16x16x32_bf16(ah, bl, acc[t], 0, 0, 0);
      acc[t] = __builtin_amdgcn_mfma_f32_16x16x32_bf16(al, bh, acc[t], 0, 0, 0);
    }
  }
  int crow0 = blockIdx.x * 64 + w * 16 + lk * 4;
#pragma unroll
  for (int t = 0; t < 8; ++t) {
    int col = t * 16 + lrow;
#pragma unroll
    for (int r = 0; r < 4; ++r) {
      int crow = crow0 + r;
      if (crow < N_NODES) C[(size_t)crow * NHID + col] = (__bf16)acc[t][r];
    }
  }
}

// ---------------- CSR build (all 4 metas, concatenated row space) ----------------
__global__ __launch_bounds__(256) void hist_all(const int* __restrict__ rows,
                                                int* __restrict__ counts) {
  int e = blockIdx.x * 256 + threadIdx.x;
  if (e < TOT_EDGES) {
    int m = e / EDGES;
    atomicAdd(&counts[m * N_NODES + rows[e]], 1);
  }
}

__global__ __launch_bounds__(256) void scan1_kernel(const int* __restrict__ counts,
                                                    int* __restrict__ row_ptr,
                                                    int* __restrict__ blk) {
  __shared__ int lds[256];
  int b = blockIdx.x, t = threadIdx.x;
  int base = b * 1024 + t * 4;
  int v[4];
  int s = 0;
#pragma unroll
  for (int k = 0; k < 4; ++k) {
    int i = base + k;
    v[k] = (i < TOT_ROWS) ? counts[i] : 0;
    s += v[k];
  }
  lds[t] = s;
  __syncthreads();
  for (int off = 1; off < 256; off <<= 1) {
    int add = (t >= off) ? lds[t - off] : 0;
    __syncthreads();
    lds[t] += add;
    __syncthreads();
  }
  int run = (t > 0) ? lds[t - 1] : 0;
  if (t == 255) blk[b] = lds[255];
#pragma unroll
  for (int k = 0; k < 4; ++k) {
    int i = base + k;
    if (i < TOT_ROWS) row_ptr[i] = run;
    run += v[k];
  }
}

__global__ void scan2_kernel(int* __restrict__ blk) {
  if (threadIdx.x == 0 && blockIdx.x == 0) {
    int run = 0;
    for (int i = 0; i < SCAN_NB; ++i) { int t = blk[i]; blk[i] = run; run += t; }
  }
}

__global__ __launch_bounds__(256) void scan3_kernel(int* __restrict__ row_ptr,
                                                    int* __restrict__ cursor,
                                                    const int* __restrict__ blk) {
  int i = blockIdx.x * 256 + threadIdx.x;
  if (i < TOT_ROWS) {
    int v = row_ptr[i] + blk[i >> 10];
    row_ptr[i] = v;
    cursor[i] = v;
  }
  if (i == 0) row_ptr[TOT_ROWS] = TOT_EDGES;
}

// single 8B store per edge (col, val)
__global__ __launch_bounds__(256) void scatter_all(const int* __restrict__ rows,
                                                   const int* __restrict__ colsin,
                                                   const float* __restrict__ valsin,
                                                   int* __restrict__ cursor,
                                                   int2* __restrict__ csr_ed) {
  int e = blockIdx.x * 256 + threadIdx.x;
  if (e >= TOT_EDGES) return;
  int m = e / EDGES;
  int pos = atomicAdd(&cursor[m * N_NODES + rows[e]], 1);
  int2 ed;
  ed.x = colsin[e];
  ed.y = __float_as_int(valsin[e]);
  csr_ed[pos] = ed;
}

// ------- layer-1 SpMM gather: 16-lane row groups, 8-deep edge unroll, fused BN stats -------
__global__ __launch_bounds__(256) void gather1_all(const int* __restrict__ row_ptr,
                                                   const int2* __restrict__ csr_ed,
                                                   const int4* __restrict__ pre1q,
                                                   int4* __restrict__ h1q,
                                                   float* __restrict__ stats) {
  __shared__ float lsum[4][16][8];
  __shared__ float lsq[4][16][8];
  int tid = threadIdx.x;
  int wv = tid >> 6, lane = tid & 63;
  int g = lane >> 4, l16 = lane & 15;
  int mm = blockIdx.y;
  int r = blockIdx.x * 16 + wv * 4 + g;
  int gr = mm * N_NODES + r;
  int start = row_ptr[gr];
  int len = row_ptr[gr + 1] - start;

  float acc[8] = {};
  int jb = 0;
  // full batches of 8 independent edges (max MLP, no masking)
  for (; jb + 8 <= len; jb += 8) {
#pragma unroll
    for (int k = 0; k < 8; ++k) {
      int2 ed = csr_ed[start + jb + k];
      float v = __int_as_float(ed.y);
      int4 p = pre1q[(size_t)ed.x * 16 + l16];
      acc[0] = fmaf(v, bfbits_lo((unsigned)p.x), acc[0]);
      acc[1] = fmaf(v, bfbits_hi((unsigned)p.x), acc[1]);
      acc[2] = fmaf(v, bfbits_lo((unsigned)p.y), acc[2]);
      acc[3] = fmaf(v, bfbits_hi((unsigned)p.y), acc[3]);
      acc[4] = fmaf(v, bfbits_lo((unsigned)p.z), acc[4]);
      acc[5] = fmaf(v, bfbits_hi((unsigned)p.z), acc[5]);
      acc[6] = fmaf(v, bfbits_lo((unsigned)p.w), acc[6]);
      acc[7] = fmaf(v, bfbits_hi((unsigned)p.w), acc[7]);
    }
  }
  // masked tail batch (clamped addresses, v zeroed)
  if (jb < len) {
#pragma unroll
    for (int k = 0; k < 8; ++k) {
      int idx = jb + k;
      int j = idx < len ? start + idx : start;
      float msk = idx < len ? 1.0f : 0.0f;
      int2 ed = csr_ed[j];
      float v = msk * __int_as_float(ed.y);
      int4 p = pre1q[(size_t)ed.x * 16 + l16];
      acc[0] = fmaf(v, bfbits_lo((unsigned)p.x), acc[0]);
      acc[1] = fmaf(v, bfbits_hi((unsigned)p.x), acc[1]);
      acc[2] = fmaf(v, bfbits_lo((unsigned)p.y), acc[2]);
      acc[3] = fmaf(v, bfbits_hi((unsigned)p.y), acc[3]);
      acc[4] = fmaf(v, bfbits_lo((unsigned)p.z), acc[4]);
      acc[5] = fmaf(v, bfbits_hi((unsigned)p.z), acc[5]);
      acc[6] = fmaf(v, bfbits_lo((unsigned)p.w), acc[6]);
      acc[7] = fmaf(v, bfbits_hi((unsigned)p.w), acc[7]);
    }
  }

  // write h1 row (bf16 packed, coalesced 256B per 16-lane group)
  int4 ho;
  ho.x = (int)pack_bf16x2(acc[0], acc[1]);
  ho.y = (int)pack_bf16x2(acc[2], acc[3]);
  ho.z = (int)pack_bf16x2(acc[4], acc[5]);
  ho.w = (int)pack_bf16x2(acc[6], acc[7]);
  h1q[(size_t)gr * 16 + l16] = ho;

  // fused BN partial stats (f32 pre-rounding)
  float sq[8];
#pragma unroll
  for (int i = 0; i < 8; ++i) sq[i] = acc[i] * acc[i];
#pragma unroll
  for (int i = 0; i < 8; ++i) {
    acc[i] += __shfl_xor(acc[i], 16);
    acc[i] += __shfl_xor(acc[i], 32);
    sq[i]  += __shfl_xor(sq[i], 16);
    sq[i]  += __shfl_xor(sq[i], 32);
  }
  if (g == 0) {
#pragma unroll
    for (int i = 0; i < 8; ++i) {
      lsum[wv][l16][i] = acc[i];
      lsq[wv][l16][i]  = sq[i];
    }
  }
  __syncthreads();
  if (tid < 128) {
    int a = tid >> 3, b = tid & 7;
    float s = lsum[0][a][b] + lsum[1][a][b] + lsum[2][a][b] + lsum[3][a][b];
    float q = lsq[0][a][b] + lsq[1][a][b] + lsq[2][a][b] + lsq[3][a][b];
    atomicAdd(&stats[mm * 256 + tid], s);
    atomicAdd(&stats[mm * 256 + 128 + tid], q);
  }
}

// ------- BN apply + relu + @W2 (all metas), 16-lane groups, int4 bf16 reads -------
__global__ __launch_bounds__(256) void bn_apply_all(const int4* __restrict__ h1q,
                                                    const float* __restrict__ stats,
                                                    const float* __restrict__ W2,
                                                    float* __restrict__ pre2) {
  int tid = threadIdx.x;
  int wv = tid >> 6, lane = tid & 63;
  int g = lane >> 4, l16 = lane & 15;
  int mm = blockIdx.y;
  int n = blockIdx.x * 16 + wv * 4 + g;
  const float inv_n = 1.0f / (float)N_NODES;
  const float* st = stats + mm * 256;
  int4 p = h1q[((size_t)mm * N_NODES + n) * 16 + l16];
  unsigned int pw[4] = {(unsigned)p.x, (unsigned)p.y, (unsigned)p.z, (unsigned)p.w};
  float c0 = 0.f, c1 = 0.f;
#pragma unroll
  for (int i = 0; i < 8; ++i) {
    int h = l16 * 8 + i;
    float xv = (i & 1) ? bfbits_hi(pw[i >> 1]) : bfbits_lo(pw[i >> 1]);
    float mean = st[h] * inv_n;
    float var = st[128 + h] * inv_n - mean * mean;
    float rs = rsqrtf(var + 1e-3f);
    float y = (xv - mean) * rs;
    y = y > 0.f ? y : 0.f;
    c0 = fmaf(y, W2[h * 2 + 0], c0);
    c1 = fmaf(y, W2[h * 2 + 1], c1);
  }
#pragma unroll
  for (int off = 1; off < 16; off <<= 1) {
    c0 += __shfl_xor(c0, off);
    c1 += __shfl_xor(c1, off);
  }
  if (l16 == 0) {
    pre2[((size_t)mm * N_NODES + n) * 2 + 0] = c0;
    pre2[((size_t)mm * N_NODES + n) * 2 + 1] = c1;
  }
}

// ---------------- layer-2 SpMM gather (all metas) ----------------
__global__ __launch_bounds__(256) void gather2_all(const int* __restrict__ row_ptr,
                                                   const int2* __restrict__ csr_ed,
                                                   const float* __restrict__ pre2,
                                                   float* __restrict__ h2) {
  int r = blockIdx.x * 256 + threadIdx.x;
  int m = blockIdx.y;
  if (r >= N_NODES) return;
  int start = row_ptr[m * N_NODES + r], end = row_ptr[m * N_NODES + r + 1];
  const float2* p2 = (const float2*)(pre2 + (size_t)m * N_NODES * 2);
  float a0 = 0.f, a1 = 0.f;
  for (int j = start; j < end; ++j) {
    int2 ed = csr_ed[j];
    float v = __int_as_float(ed.y);
    float2 p = p2[ed.x];
    a0 = fmaf(v, p.x, a0);
    a1 = fmaf(v, p.y, a1);
  }
  h2[((size_t)m * N_NODES + r) * 2 + 0] = a0;
  h2[((size_t)m * N_NODES + r) * 2 + 1] = a1;
}

// ---------------- attention dot ----------------
__global__ __launch_bounds__(256) void att_dot_kernel(const float* __restrict__ h2,
                                                      const float* __restrict__ w_omega,
                                                      float* __restrict__ vacc) {
  float acc[16] = {};
  int stride = gridDim.x * blockDim.x;
  for (int i = blockIdx.x * blockDim.x + threadIdx.x; i < N_NODES * NCLS; i += stride) {
    float4 w = *reinterpret_cast<const float4*>(&w_omega[(size_t)i * 4]);
#pragma unroll
    for (int m = 0; m < 4; ++m) {
      float f = h2[(size_t)m * (N_NODES * NCLS) + i];
      acc[m * 4 + 0] = fmaf(f, w.x, acc[m * 4 + 0]);
      acc[m * 4 + 1] = fmaf(f, w.y, acc[m * 4 + 1]);
      acc[m * 4 + 2] = fmaf(f, w.z, acc[m * 4 + 2]);
      acc[m * 4 + 3] = fmaf(f, w.w, acc[m * 4 + 3]);
    }
  }
#pragma unroll
  for (int q = 0; q < 16; ++q) {
    float v = acc[q];
    for (int off = 32; off; off >>= 1) v += __shfl_down(v, off);
    if ((threadIdx.x & 63) == 0) atomicAdd(&vacc[q], v);
  }
}

// ---------------- attention finalize ----------------
__global__ void att_final_kernel(const float* __restrict__ vacc,
                                 const float* __restrict__ b_omega,
                                 const float* __restrict__ u_omega,
                                 float* __restrict__ alphas) {
  if (threadIdx.x == 0 && blockIdx.x == 0) {
    float s[4];
    for (int m = 0; m < 4; ++m) {
      float sm = 0.f;
      for (int j = 0; j < 4; ++j)
        sm += tanhf(vacc[m * 4 + j] + b_omega[j]) * u_omega[j];
      s[m] = sm;
    }
    float mx = fmaxf(fmaxf(s[0], s[1]), fmaxf(s[2], s[3]));
    float ex[4], den = 0.f;
    for (int m = 0; m < 4; ++m) { ex[m] = expf(s[m] - mx); den += ex[m]; }
    for (int m = 0; m < 4; ++m) alphas[m] = ex[m] / den;
  }
}

// ---------------- fused sum of squares over all 5 params ----------------
#define SQ0 400000            // w_omega
#define SQ1 (SQ0 + 65536)     // + W1
#define SQ2 (SQ1 + 256)       // + W2
#define SQ3 (SQ2 + 4)         // + b_omega
#define SQ4 (SQ3 + 4)         // + u_omega
__global__ __launch_bounds__(256) void sumsq_all(const float* __restrict__ w_omega,
                                                 const float* __restrict__ W1,
                                                 const float* __restrict__ W2,
                                                 const float* __restrict__ b_omega,
                                                 const float* __restrict__ u_omega,
                                                 float* __restrict__ out) {
  float s = 0.f;
  int stride = gridDim.x * blockDim.x;
  for (int i = blockIdx.x * blockDim.x + threadIdx.x; i < SQ4; i += stride) {
    float v;
    if (i < SQ0) v = w_omega[i];
    else if (i < SQ1) v = W1[i - SQ0];
    else if (i < SQ2) v = W2[i - SQ1];
    else if (i < SQ3) v = b_omega[i - SQ2];
    else v = u_omega[i - SQ3];
    s = fmaf(v, v, s);
  }
  for (int off = 32; off; off >>= 1) s += __shfl_down(s, off);
  if ((threadIdx.x & 63) == 0) atomicAdd(out, s);
}

// ---------------- per-node CE / acc / mask sums ----------------
__global__ __launch_bounds__(256) void loss_kernel(const float* __restrict__ h2,
                                                   const float* __restrict__ alphas,
                                                   const float* __restrict__ label,
                                                   const float* __restrict__ mask,
                                                   float* __restrict__ scal) {
  int n = blockIdx.x * blockDim.x + threadIdx.x;
  float msum = 0.f, cesum = 0.f, accsum = 0.f;
  if (n < N_NODES) {
    float a0 = alphas[0], a1 = alphas[1], a2 = alphas[2], a3 = alphas[3];
    const int S = N_NODES * NCLS;
    float l0 = a0 * h2[n * 2] + a1 * h2[S + n * 2] + a2 * h2[2 * S + n * 2] + a3 * h2[3 * S + n * 2];
    float l1 = a0 * h2[n * 2 + 1] + a1 * h2[S + n * 2 + 1] + a2 * h2[2 * S + n * 2 + 1] + a3 * h2[3 * S + n * 2 + 1];
    float mx = fmaxf(l0, l1);
    float lse = mx + logf(expf(l0 - mx) + expf(l1 - mx));
    float lb0 = label[n * 2], lb1 = label[n * 2 + 1];
    float ce = -(lb0 * (l0 - lse) + lb1 * (l1 - lse));
    int pred = (l1 > l0) ? 1 : 0;
    int larg = (lb1 > lb0) ? 1 : 0;
    float corr = (pred == larg) ? 1.f : 0.f;
    float mk = mask[n];
    msum = mk;
    cesum = ce * mk;
    accsum = corr * mk;
  }
  for (int off = 32; off; off >>= 1) {
    msum += __shfl_down(msum, off);
    cesum += __shfl_down(cesum, off);
    accsum += __shfl_down(accsum, off);
  }
  if ((threadIdx.x & 63) == 0) {
    atomicAdd(&scal[0], msum);
    atomicAdd(&scal[1], cesum);
    atomicAdd(&scal[2], accsum);
  }
}

__global__ void final_kernel(const float* __restrict__ scal, float* __restrict__ out) {
  if (threadIdx.x == 0 && blockIdx.x == 0) {
    out[0] = 5e-4f * 0.5f * scal[3] + scal[1] / scal[0];
    out[1] = scal[2] / scal[0];
  }
}

extern "C" void kernel_launch(void* const* d_in, const int* in_sizes, int n_in,
                              void* d_out, int out_size, void* d_ws, size_t ws_size,
                              hipStream_t stream) {
  const float* x       = (const float*)d_in[0];
  const float* W1      = (const float*)d_in[1];
  const float* W2      = (const float*)d_in[2];
  const float* w_omega = (const float*)d_in[3];
  const float* b_omega = (const float*)d_in[4];
  const float* u_omega = (const float*)d_in[5];
  const int*   sup_rows = (const int*)d_in[6];
  const int*   sup_cols = (const int*)d_in[7];
  const float* sup_vals = (const float*)d_in[8];
  const float* label   = (const float*)d_in[9];
  const float* mask    = (const float*)d_in[10];
  float* out = (float*)d_out;

  float* ws = (float*)d_ws;
  // offsets in floats
  __bf16* pre1b   = (__bf16*)ws;                 // [N][128] bf16 = 3.2M f
  int4*   h1q     = (int4*)(ws + 3200000);       // [META][N][16] int4 = 12.8M f
  float*  pre2    = ws + 16000000;               // 400k f [META][N][2]
  float*  h2      = ws + 16400000;               // 400k f [META][N][2]
  int2*   csr_ed  = (int2*)(ws + 16800000);      // 3.2M int2 = 6.4M f
  int*    row_ptr = (int*)(ws + 23200000);       // 200,001
  int*    cursor  = (int*)(ws + 23400064);       // 200,000
  int*    counts  = (int*)(ws + 23600064);       // 200,000
  int*    blk     = (int*)(ws + 23800064);       // 256
  float*  stats   = ws + 23800320;               // 1024 [META][256]
  float*  scal    = ws + 23801344;               // 8
  float*  vacc    = ws + 23801352;               // 16
  float*  alphas  = ws + 23801368;               // 4
  __bf16* Wh      = (__bf16*)(ws + 23801372);    // 65536 bf16
  __bf16* Wl      = (__bf16*)(ws + 23834140);    // 65536 bf16

  // ---- GEMM path ----
  pack_w1<<<dim3(32), dim3(256), 0, stream>>>(W1, Wh, Wl);
  gemm_mfma<<<dim3(782), dim3(256), 0, stream>>>(x, Wh, Wl, pre1b);

  // ---- zero counters + stats/scal/vacc ----
  hipMemsetAsync(counts, 0, TOT_ROWS * sizeof(int), stream);
  hipMemsetAsync(stats, 0, (1024 + 8 + 16) * sizeof(float), stream);

  // ---- CSR build, all 4 metas ----
  hist_all<<<dim3(12500), dim3(256), 0, stream>>>(sup_rows, counts);
  scan1_kernel<<<dim3(SCAN_NB), dim3(256), 0, stream>>>(counts, row_ptr, blk);
  scan2_kernel<<<dim3(1), dim3(64), 0, stream>>>(blk);
  scan3_kernel<<<dim3(782), dim3(256), 0, stream>>>(row_ptr, cursor, blk);
  scatter_all<<<dim3(12500), dim3(256), 0, stream>>>(sup_rows, sup_cols, sup_vals,
                                                     cursor, csr_ed);

  // ---- layer-1 gather (+fused BN stats), all metas, 16 rows/block ----
  gather1_all<<<dim3(3125, META), dim3(256), 0, stream>>>(
      row_ptr, csr_ed, (const int4*)pre1b, h1q, stats);

  // ---- BN apply + W2, all metas ----
  bn_apply_all<<<dim3(3125, META), dim3(256), 0, stream>>>(h1q, stats, W2, pre2);

  // ---- layer-2 gather, all metas ----
  gather2_all<<<dim3(196, META), dim3(256), 0, stream>>>(row_ptr, csr_ed, pre2, h2);

  att_dot_kernel<<<dim3(64), dim3(256), 0, stream>>>(h2, w_omega, vacc);
  att_final_kernel<<<dim3(1), dim3(64), 0, stream>>>(vacc, b_omega, u_omega, alphas);

  sumsq_all<<<dim3(128), dim3(256), 0, stream>>>(w_omega, W1, W2, b_omega, u_omega, scal + 3);

  loss_kernel<<<dim3(196), dim3(256), 0, stream>>>(h2, alphas, label, mask, scal);
  final_kernel<<<dim3(1), dim3(64), 0, stream>>>(scal, out);
}

// Round 7
// 714.903 us; speedup vs baseline: 4.5376x; 1.1521x over previous
//
#include <hip/hip_runtime.h>
#include <hip/hip_bf16.h>
#include <math.h>

#define N_NODES 50000
#define EDGES   800000
#define META    4
#define IN_DIM  512
#define NHID    128
#define NCLS    2
#define TOT_ROWS  (META * N_NODES)   // 200000
#define TOT_EDGES (META * EDGES)     // 3200000
#define SCAN_NB 196                  // ceil(200000/1024)
#define EPB 2048                     // edges per slice (hist/scatter)
#define NSLICE ((TOT_EDGES + EPB - 1) / EPB)  // 1563
#define NGRP 8                       // XCD groups
#define ROWS_PER_GRP (TOT_ROWS / NGRP) // 25000

typedef __bf16 bf16x8 __attribute__((ext_vector_type(8)));
typedef float  f32x4  __attribute__((ext_vector_type(4)));

__device__ __forceinline__ float bfbits_lo(unsigned int p) {
  return __uint_as_float((p & 0xFFFFu) << 16);
}
__device__ __forceinline__ float bfbits_hi(unsigned int p) {
  return __uint_as_float(p & 0xFFFF0000u);
}
__device__ __forceinline__ unsigned int pack_bf16x2(float a, float b) {
  __bf16 ba = (__bf16)a, bb = (__bf16)b;
  return ((unsigned int)__builtin_bit_cast(unsigned short, bb) << 16) |
         (unsigned int)__builtin_bit_cast(unsigned short, ba);
}

// ---------------- pack W1 into MFMA-fragment-ready bf16 hi/lo ----------------
__global__ __launch_bounds__(256) void pack_w1(const float* __restrict__ W1,
                                               __bf16* __restrict__ Wh,
                                               __bf16* __restrict__ Wl) {
  int idx = blockIdx.x * 256 + threadIdx.x;
  if (idx >= 16 * 8 * 64) return;
  int l = idx & 63, st = idx >> 6, t = st & 7, s = st >> 3;
  int col = t * 16 + (l & 15);
  int k0 = s * 32 + (l >> 4) * 8;
#pragma unroll
  for (int i = 0; i < 8; ++i) {
    float w = W1[(size_t)(k0 + i) * NHID + col];
    __bf16 h = (__bf16)w;
    Wh[(size_t)idx * 8 + i] = h;
    Wl[(size_t)idx * 8 + i] = (__bf16)(w - (float)h);
  }
}

// ---------------- GEMM: pre1 = x @ W1 via bf16x3 MFMA, bf16 output ----------------
__global__ __launch_bounds__(256) void gemm_mfma(const float* __restrict__ X,
                                                 const __bf16* __restrict__ Wh,
                                                 const __bf16* __restrict__ Wl,
                                                 __bf16* __restrict__ C) {
  int w = threadIdx.x >> 6, l = threadIdx.x & 63;
  int lrow = l & 15, lk = l >> 4;
  int row = blockIdx.x * 64 + w * 16 + lrow;
  int rowc = row < N_NODES ? row : N_NODES - 1;
  f32x4 acc[8] = {};
  const bf16x8* whv = (const bf16x8*)Wh;
  const bf16x8* wlv = (const bf16x8*)Wl;

  for (int s = 0; s < 16; ++s) {
    const float* ap = &X[(size_t)rowc * IN_DIM + s * 32 + lk * 8];
    float4 a0 = *reinterpret_cast<const float4*>(ap);
    float4 a1 = *reinterpret_cast<const float4*>(ap + 4);
    float av[8] = {a0.x, a0.y, a0.z, a0.w, a1.x, a1.y, a1.z, a1.w};
    bf16x8 ah, al;
#pragma unroll
    for (int i = 0; i < 8; ++i) {
      float v = av[i];
      __bf16 h = (__bf16)v;
      ah[i] = h;
      al[i] = (__bf16)(v - (float)h);
    }
    int fbase = (s * 8) * 64 + l;
#pragma unroll
    for (int t = 0; t < 8; ++t) {
      bf16x8 bh = whv[fbase + t * 64];
      bf16x8 bl = wlv[fbase + t * 64];
      acc[t] = __builtin_amdgcn_mfma_f32_16x16x32_bf16(ah, bh, acc[t], 0, 0, 0);
      acc[t] = __builtin_amdgcn_mfma_f32_16x16x32_bf16(ah, bl, acc[t], 0, 0, 0);
      acc[t] = __builtin_amdgcn_mfma_f32_16x16x32_bf16(al, bh, acc[t], 0, 0, 0);
    }
  }
  int crow0 = blockIdx.x * 64 + w * 16 + lk * 4;
#pragma unroll
  for (int t = 0; t < 8; ++t) {
    int col = t * 16 + lrow;
#pragma unroll
    for (int r = 0; r < 4; ++r) {
      int crow = crow0 + r;
      if (crow < N_NODES) C[(size_t)crow * NHID + col] = (__bf16)acc[t][r];
    }
  }
}

// ------- CSR build: XCD-filtered histogram (each group counts only its row chunk) -------
__global__ __launch_bounds__(256) void hist_all(const int* __restrict__ rows,
                                                int* __restrict__ counts) {
  int flat = blockIdx.x;
  int g = flat & (NGRP - 1);       // XCD group (blocks round-robin across XCDs)
  int slice = flat >> 3;
  int e0 = slice * EPB;
  int lo = g * ROWS_PER_GRP, hi = lo + ROWS_PER_GRP;
#pragma unroll
  for (int t = 0; t < EPB / 256; ++t) {
    int e = e0 + t * 256 + threadIdx.x;
    if (e < TOT_EDGES) {
      int m = e / EDGES;
      int gr = m * N_NODES + rows[e];
      if (gr >= lo && gr < hi) atomicAdd(&counts[gr], 1);
    }
  }
}

__global__ __launch_bounds__(256) void scan1_kernel(const int* __restrict__ counts,
                                                    int* __restrict__ row_ptr,
                                                    int* __restrict__ blk) {
  __shared__ int lds[256];
  int b = blockIdx.x, t = threadIdx.x;
  int base = b * 1024 + t * 4;
  int v[4];
  int s = 0;
#pragma unroll
  for (int k = 0; k < 4; ++k) {
    int i = base + k;
    v[k] = (i < TOT_ROWS) ? counts[i] : 0;
    s += v[k];
  }
  lds[t] = s;
  __syncthreads();
  for (int off = 1; off < 256; off <<= 1) {
    int add = (t >= off) ? lds[t - off] : 0;
    __syncthreads();
    lds[t] += add;
    __syncthreads();
  }
  int run = (t > 0) ? lds[t - 1] : 0;
  if (t == 255) blk[b] = lds[255];
#pragma unroll
  for (int k = 0; k < 4; ++k) {
    int i = base + k;
    if (i < TOT_ROWS) row_ptr[i] = run;
    run += v[k];
  }
}

__global__ void scan2_kernel(int* __restrict__ blk) {
  if (threadIdx.x == 0 && blockIdx.x == 0) {
    int run = 0;
    for (int i = 0; i < SCAN_NB; ++i) { int t = blk[i]; blk[i] = run; run += t; }
  }
}

__global__ __launch_bounds__(256) void scan3_kernel(int* __restrict__ row_ptr,
                                                    int* __restrict__ cursor,
                                                    const int* __restrict__ blk) {
  int i = blockIdx.x * 256 + threadIdx.x;
  if (i < TOT_ROWS) {
    int v = row_ptr[i] + blk[i >> 10];
    row_ptr[i] = v;
    cursor[i] = v;
  }
  if (i == 0) row_ptr[TOT_ROWS] = TOT_EDGES;
}

// ------- CSR build: XCD-filtered scatter (group g writes only its contiguous CSR chunk) -------
__global__ __launch_bounds__(256) void scatter_all(const int* __restrict__ rows,
                                                   const int* __restrict__ colsin,
                                                   const float* __restrict__ valsin,
                                                   int* __restrict__ cursor,
                                                   int2* __restrict__ csr_ed) {
  int flat = blockIdx.x;
  int g = flat & (NGRP - 1);
  int slice = flat >> 3;
  int e0 = slice * EPB;
  int lo = g * ROWS_PER_GRP, hi = lo + ROWS_PER_GRP;
#pragma unroll
  for (int t = 0; t < EPB / 256; ++t) {
    int e = e0 + t * 256 + threadIdx.x;
    if (e < TOT_EDGES) {
      int m = e / EDGES;
      int gr = m * N_NODES + rows[e];
      if (gr >= lo && gr < hi) {
        int pos = atomicAdd(&cursor[gr], 1);
        int2 ed;
        ed.x = colsin[e];
        ed.y = __float_as_int(valsin[e]);
        csr_ed[pos] = ed;
      }
    }
  }
}

// ------- layer-1 SpMM gather: 16-lane row groups, 8-deep edge unroll, fused BN stats -------
__global__ __launch_bounds__(256) void gather1_all(const int* __restrict__ row_ptr,
                                                   const int2* __restrict__ csr_ed,
                                                   const int4* __restrict__ pre1q,
                                                   int4* __restrict__ h1q,
                                                   float* __restrict__ stats) {
  __shared__ float lsum[4][16][8];
  __shared__ float lsq[4][16][8];
  int tid = threadIdx.x;
  int wv = tid >> 6, lane = tid & 63;
  int g = lane >> 4, l16 = lane & 15;
  int mm = blockIdx.y;
  int r = blockIdx.x * 16 + wv * 4 + g;
  int gr = mm * N_NODES + r;
  int start = row_ptr[gr];
  int len = row_ptr[gr + 1] - start;

  float acc[8] = {};
  int jb = 0;
  for (; jb + 8 <= len; jb += 8) {
#pragma unroll
    for (int k = 0; k < 8; ++k) {
      int2 ed = csr_ed[start + jb + k];
      float v = __int_as_float(ed.y);
      int4 p = pre1q[(size_t)ed.x * 16 + l16];
      acc[0] = fmaf(v, bfbits_lo((unsigned)p.x), acc[0]);
      acc[1] = fmaf(v, bfbits_hi((unsigned)p.x), acc[1]);
      acc[2] = fmaf(v, bfbits_lo((unsigned)p.y), acc[2]);
      acc[3] = fmaf(v, bfbits_hi((unsigned)p.y), acc[3]);
      acc[4] = fmaf(v, bfbits_lo((unsigned)p.z), acc[4]);
      acc[5] = fmaf(v, bfbits_hi((unsigned)p.z), acc[5]);
      acc[6] = fmaf(v, bfbits_lo((unsigned)p.w), acc[6]);
      acc[7] = fmaf(v, bfbits_hi((unsigned)p.w), acc[7]);
    }
  }
  if (jb < len) {
#pragma unroll
    for (int k = 0; k < 8; ++k) {
      int idx = jb + k;
      int j = idx < len ? start + idx : start;
      float msk = idx < len ? 1.0f : 0.0f;
      int2 ed = csr_ed[j];
      float v = msk * __int_as_float(ed.y);
      int4 p = pre1q[(size_t)ed.x * 16 + l16];
      acc[0] = fmaf(v, bfbits_lo((unsigned)p.x), acc[0]);
      acc[1] = fmaf(v, bfbits_hi((unsigned)p.x), acc[1]);
      acc[2] = fmaf(v, bfbits_lo((unsigned)p.y), acc[2]);
      acc[3] = fmaf(v, bfbits_hi((unsigned)p.y), acc[3]);
      acc[4] = fmaf(v, bfbits_lo((unsigned)p.z), acc[4]);
      acc[5] = fmaf(v, bfbits_hi((unsigned)p.z), acc[5]);
      acc[6] = fmaf(v, bfbits_lo((unsigned)p.w), acc[6]);
      acc[7] = fmaf(v, bfbits_hi((unsigned)p.w), acc[7]);
    }
  }

  int4 ho;
  ho.x = (int)pack_bf16x2(acc[0], acc[1]);
  ho.y = (int)pack_bf16x2(acc[2], acc[3]);
  ho.z = (int)pack_bf16x2(acc[4], acc[5]);
  ho.w = (int)pack_bf16x2(acc[6], acc[7]);
  h1q[(size_t)gr * 16 + l16] = ho;

  float sq[8];
#pragma unroll
  for (int i = 0; i < 8; ++i) sq[i] = acc[i] * acc[i];
#pragma unroll
  for (int i = 0; i < 8; ++i) {
    acc[i] += __shfl_xor(acc[i], 16);
    acc[i] += __shfl_xor(acc[i], 32);
    sq[i]  += __shfl_xor(sq[i], 16);
    sq[i]  += __shfl_xor(sq[i], 32);
  }
  if (g == 0) {
#pragma unroll
    for (int i = 0; i < 8; ++i) {
      lsum[wv][l16][i] = acc[i];
      lsq[wv][l16][i]  = sq[i];
    }
  }
  __syncthreads();
  if (tid < 128) {
    int a = tid >> 3, b = tid & 7;
    float s = lsum[0][a][b] + lsum[1][a][b] + lsum[2][a][b] + lsum[3][a][b];
    float q = lsq[0][a][b] + lsq[1][a][b] + lsq[2][a][b] + lsq[3][a][b];
    atomicAdd(&stats[mm * 256 + tid], s);
    atomicAdd(&stats[mm * 256 + 128 + tid], q);
  }
}

// ------- BN apply + relu + @W2 (all metas), 16-lane groups, int4 bf16 reads -------
__global__ __launch_bounds__(256) void bn_apply_all(const int4* __restrict__ h1q,
                                                    const float* __restrict__ stats,
                                                    const float* __restrict__ W2,
                                                    float* __restrict__ pre2) {
  int tid = threadIdx.x;
  int wv = tid >> 6, lane = tid & 63;
  int g = lane >> 4, l16 = lane & 15;
  int mm = blockIdx.y;
  int n = blockIdx.x * 16 + wv * 4 + g;
  const float inv_n = 1.0f / (float)N_NODES;
  const float* st = stats + mm * 256;
  int4 p = h1q[((size_t)mm * N_NODES + n) * 16 + l16];
  unsigned int pw[4] = {(unsigned)p.x, (unsigned)p.y, (unsigned)p.z, (unsigned)p.w};
  float c0 = 0.f, c1 = 0.f;
#pragma unroll
  for (int i = 0; i < 8; ++i) {
    int h = l16 * 8 + i;
    float xv = (i & 1) ? bfbits_hi(pw[i >> 1]) : bfbits_lo(pw[i >> 1]);
    float mean = st[h] * inv_n;
    float var = st[128 + h] * inv_n - mean * mean;
    float rs = rsqrtf(var + 1e-3f);
    float y = (xv - mean) * rs;
    y = y > 0.f ? y : 0.f;
    c0 = fmaf(y, W2[h * 2 + 0], c0);
    c1 = fmaf(y, W2[h * 2 + 1], c1);
  }
#pragma unroll
  for (int off = 1; off < 16; off <<= 1) {
    c0 += __shfl_xor(c0, off);
    c1 += __shfl_xor(c1, off);
  }
  if (l16 == 0) {
    pre2[((size_t)mm * N_NODES + n) * 2 + 0] = c0;
    pre2[((size_t)mm * N_NODES + n) * 2 + 1] = c1;
  }
}

// ---------------- layer-2 SpMM gather (all metas), 8-deep unroll ----------------
__global__ __launch_bounds__(256) void gather2_all(const int* __restrict__ row_ptr,
                                                   const int2* __restrict__ csr_ed,
                                                   const float* __restrict__ pre2,
                                                   float* __restrict__ h2) {
  int r = blockIdx.x * 256 + threadIdx.x;
  int m = blockIdx.y;
  if (r >= N_NODES) return;
  int start = row_ptr[m * N_NODES + r];
  int len = row_ptr[m * N_NODES + r + 1] - start;
  const float2* p2 = (const float2*)(pre2 + (size_t)m * N_NODES * 2);
  float a0 = 0.f, a1 = 0.f;
  int jb = 0;
  for (; jb + 8 <= len; jb += 8) {
#pragma unroll
    for (int k = 0; k < 8; ++k) {
      int2 ed = csr_ed[start + jb + k];
      float v = __int_as_float(ed.y);
      float2 p = p2[ed.x];
      a0 = fmaf(v, p.x, a0);
      a1 = fmaf(v, p.y, a1);
    }
  }
  if (jb < len) {
#pragma unroll
    for (int k = 0; k < 8; ++k) {
      int idx = jb + k;
      int j = idx < len ? start + idx : start;
      float msk = idx < len ? 1.0f : 0.0f;
      int2 ed = csr_ed[j];
      float v = msk * __int_as_float(ed.y);
      float2 p = p2[ed.x];
      a0 = fmaf(v, p.x, a0);
      a1 = fmaf(v, p.y, a1);
    }
  }
  h2[((size_t)m * N_NODES + r) * 2 + 0] = a0;
  h2[((size_t)m * N_NODES + r) * 2 + 1] = a1;
}

// ---------------- attention dot ----------------
__global__ __launch_bounds__(256) void att_dot_kernel(const float* __restrict__ h2,
                                                      const float* __restrict__ w_omega,
                                                      float* __restrict__ vacc) {
  float acc[16] = {};
  int stride = gridDim.x * blockDim.x;
  for (int i = blockIdx.x * blockDim.x + threadIdx.x; i < N_NODES * NCLS; i += stride) {
    float4 w = *reinterpret_cast<const float4*>(&w_omega[(size_t)i * 4]);
#pragma unroll
    for (int m = 0; m < 4; ++m) {
      float f = h2[(size_t)m * (N_NODES * NCLS) + i];
      acc[m * 4 + 0] = fmaf(f, w.x, acc[m * 4 + 0]);
      acc[m * 4 + 1] = fmaf(f, w.y, acc[m * 4 + 1]);
      acc[m * 4 + 2] = fmaf(f, w.z, acc[m * 4 + 2]);
      acc[m * 4 + 3] = fmaf(f, w.w, acc[m * 4 + 3]);
    }
  }
#pragma unroll
  for (int q = 0; q < 16; ++q) {
    float v = acc[q];
    for (int off = 32; off; off >>= 1) v += __shfl_down(v, off);
    if ((threadIdx.x & 63) == 0) atomicAdd(&vacc[q], v);
  }
}

// ---------------- attention finalize ----------------
__global__ void att_final_kernel(const float* __restrict__ vacc,
                                 const float* __restrict__ b_omega,
                                 const float* __restrict__ u_omega,
                                 float* __restrict__ alphas) {
  if (threadIdx.x == 0 && blockIdx.x == 0) {
    float s[4];
    for (int m = 0; m < 4; ++m) {
      float sm = 0.f;
      for (int j = 0; j < 4; ++j)
        sm += tanhf(vacc[m * 4 + j] + b_omega[j]) * u_omega[j];
      s[m] = sm;
    }
    float mx = fmaxf(fmaxf(s[0], s[1]), fmaxf(s[2], s[3]));
    float ex[4], den = 0.f;
    for (int m = 0; m < 4; ++m) { ex[m] = expf(s[m] - mx); den += ex[m]; }
    for (int m = 0; m < 4; ++m) alphas[m] = ex[m] / den;
  }
}

// ---------------- fused sum of squares over all 5 params ----------------
#define SQ0 400000            // w_omega
#define SQ1 (SQ0 + 65536)     // + W1
#define SQ2 (SQ1 + 256)       // + W2
#define SQ3 (SQ2 + 4)         // + b_omega
#define SQ4 (SQ3 + 4)         // + u_omega
__global__ __launch_bounds__(256) void sumsq_all(const float* __restrict__ w_omega,
                                                 const float* __restrict__ W1,
                                                 const float* __restrict__ W2,
                                                 const float* __restrict__ b_omega,
                                                 const float* __restrict__ u_omega,
                                                 float* __restrict__ out) {
  float s = 0.f;
  int stride = gridDim.x * blockDim.x;
  for (int i = blockIdx.x * blockDim.x + threadIdx.x; i < SQ4; i += stride) {
    float v;
    if (i < SQ0) v = w_omega[i];
    else if (i < SQ1) v = W1[i - SQ0];
    else if (i < SQ2) v = W2[i - SQ1];
    else if (i < SQ3) v = b_omega[i - SQ2];
    else v = u_omega[i - SQ3];
    s = fmaf(v, v, s);
  }
  for (int off = 32; off; off >>= 1) s += __shfl_down(s, off);
  if ((threadIdx.x & 63) == 0) atomicAdd(out, s);
}

// ---------------- per-node CE / acc / mask sums ----------------
__global__ __launch_bounds__(256) void loss_kernel(const float* __restrict__ h2,
                                                   const float* __restrict__ alphas,
                                                   const float* __restrict__ label,
                                                   const float* __restrict__ mask,
                                                   float* __restrict__ scal) {
  int n = blockIdx.x * blockDim.x + threadIdx.x;
  float msum = 0.f, cesum = 0.f, accsum = 0.f;
  if (n < N_NODES) {
    float a0 = alphas[0], a1 = alphas[1], a2 = alphas[2], a3 = alphas[3];
    const int S = N_NODES * NCLS;
    float l0 = a0 * h2[n * 2] + a1 * h2[S + n * 2] + a2 * h2[2 * S + n * 2] + a3 * h2[3 * S + n * 2];
    float l1 = a0 * h2[n * 2 + 1] + a1 * h2[S + n * 2 + 1] + a2 * h2[2 * S + n * 2 + 1] + a3 * h2[3 * S + n * 2 + 1];
    float mx = fmaxf(l0, l1);
    float lse = mx + logf(expf(l0 - mx) + expf(l1 - mx));
    float lb0 = label[n * 2], lb1 = label[n * 2 + 1];
    float ce = -(lb0 * (l0 - lse) + lb1 * (l1 - lse));
    int pred = (l1 > l0) ? 1 : 0;
    int larg = (lb1 > lb0) ? 1 : 0;
    float corr = (pred == larg) ? 1.f : 0.f;
    float mk = mask[n];
    msum = mk;
    cesum = ce * mk;
    accsum = corr * mk;
  }
  for (int off = 32; off; off >>= 1) {
    msum += __shfl_down(msum, off);
    cesum += __shfl_down(cesum, off);
    accsum += __shfl_down(accsum, off);
  }
  if ((threadIdx.x & 63) == 0) {
    atomicAdd(&scal[0], msum);
    atomicAdd(&scal[1], cesum);
    atomicAdd(&scal[2], accsum);
  }
}

__global__ void final_kernel(const float* __restrict__ scal, float* __restrict__ out) {
  if (threadIdx.x == 0 && blockIdx.x == 0) {
    out[0] = 5e-4f * 0.5f * scal[3] + scal[1] / scal[0];
    out[1] = scal[2] / scal[0];
  }
}

extern "C" void kernel_launch(void* const* d_in, const int* in_sizes, int n_in,
                              void* d_out, int out_size, void* d_ws, size_t ws_size,
                              hipStream_t stream) {
  const float* x       = (const float*)d_in[0];
  const float* W1      = (const float*)d_in[1];
  const float* W2      = (const float*)d_in[2];
  const float* w_omega = (const float*)d_in[3];
  const float* b_omega = (const float*)d_in[4];
  const float* u_omega = (const float*)d_in[5];
  const int*   sup_rows = (const int*)d_in[6];
  const int*   sup_cols = (const int*)d_in[7];
  const float* sup_vals = (const float*)d_in[8];
  const float* label   = (const float*)d_in[9];
  const float* mask    = (const float*)d_in[10];
  float* out = (float*)d_out;

  float* ws = (float*)d_ws;
  // offsets in floats
  __bf16* pre1b   = (__bf16*)ws;                 // [N][128] bf16 = 3.2M f
  int4*   h1q     = (int4*)(ws + 3200000);       // [META][N][16] int4 = 12.8M f
  float*  pre2    = ws + 16000000;               // 400k f [META][N][2]
  float*  h2      = ws + 16400000;               // 400k f [META][N][2]
  int2*   csr_ed  = (int2*)(ws + 16800000);      // 3.2M int2 = 6.4M f
  int*    row_ptr = (int*)(ws + 23200000);       // 200,001
  int*    cursor  = (int*)(ws + 23400064);       // 200,000
  int*    counts  = (int*)(ws + 23600064);       // 200,000
  int*    blk     = (int*)(ws + 23800064);       // 256
  float*  stats   = ws + 23800320;               // 1024 [META][256]
  float*  scal    = ws + 23801344;               // 8
  float*  vacc    = ws + 23801352;               // 16
  float*  alphas  = ws + 23801368;               // 4
  __bf16* Wh      = (__bf16*)(ws + 23801372);    // 65536 bf16
  __bf16* Wl      = (__bf16*)(ws + 23834140);    // 65536 bf16

  // ---- GEMM path ----
  pack_w1<<<dim3(32), dim3(256), 0, stream>>>(W1, Wh, Wl);
  gemm_mfma<<<dim3(782), dim3(256), 0, stream>>>(x, Wh, Wl, pre1b);

  // ---- zero counters + stats/scal/vacc ----
  hipMemsetAsync(counts, 0, TOT_ROWS * sizeof(int), stream);
  hipMemsetAsync(stats, 0, (1024 + 8 + 16) * sizeof(float), stream);

  // ---- CSR build, all 4 metas, XCD-filtered hist + scatter ----
  hist_all<<<dim3(NSLICE * NGRP), dim3(256), 0, stream>>>(sup_rows, counts);
  scan1_kernel<<<dim3(SCAN_NB), dim3(256), 0, stream>>>(counts, row_ptr, blk);
  scan2_kernel<<<dim3(1), dim3(64), 0, stream>>>(blk);
  scan3_kernel<<<dim3(782), dim3(256), 0, stream>>>(row_ptr, cursor, blk);
  scatter_all<<<dim3(NSLICE * NGRP), dim3(256), 0, stream>>>(sup_rows, sup_cols, sup_vals,
                                                             cursor, csr_ed);

  // ---- layer-1 gather (+fused BN stats), all metas, 16 rows/block ----
  gather1_all<<<dim3(3125, META), dim3(256), 0, stream>>>(
      row_ptr, csr_ed, (const int4*)pre1b, h1q, stats);

  // ---- BN apply + W2, all metas ----
  bn_apply_all<<<dim3(3125, META), dim3(256), 0, stream>>>(h1q, stats, W2, pre2);

  // ---- layer-2 gather, all metas ----
  gather2_all<<<dim3(196, META), dim3(256), 0, stream>>>(row_ptr, csr_ed, pre2, h2);

  att_dot_kernel<<<dim3(64), dim3(256), 0, stream>>>(h2, w_omega, vacc);
  att_final_kernel<<<dim3(1), dim3(64), 0, stream>>>(vacc, b_omega, u_omega, alphas);

  sumsq_all<<<dim3(128), dim3(256), 0, stream>>>(w_omega, W1, W2, b_omega, u_omega, scal + 3);

  loss_kernel<<<dim3(196), dim3(256), 0, stream>>>(h2, alphas, label, mask, scal);
  final_kernel<<<dim3(1), dim3(64), 0, stream>>>(scal, out);
}